// Round 6
// baseline (88.461 us; speedup 1.0000x reference)
//
#include <hip/hip_runtime.h>

#define NA 8192
#define IT 128                          // i-atoms per wave-job (2 per lane, packed)
#define JT 64                           // j-atoms per wave-job (1 per lane, readlane-fed)
#define NI (NA / IT)                    // 64 i-tile rows
#define NJOB 4160                       // sum_{I=0..63} (128 - 2I) jobs with J >= 2I
#define WPB 4                           // waves per block
#define BLOCK (WPB * 64)                // 256 threads
#define NBLK (NJOB / WPB)               // 1040 blocks (divides exactly)
#define S_OF(I) ((I) * (129 - (I)))     // jobs before i-tile row I

typedef float v2f __attribute__((ext_vector_type(2)));

__device__ __forceinline__ float bcast(float v, int k) {
    return __int_as_float(__builtin_amdgcn_readlane(__float_as_int(v), k));
}

__global__ __launch_bounds__(BLOCK, 6) void dftd3_pair_energy(
    const float* __restrict__ pos,
    const float* __restrict__ p_a1, const float* __restrict__ p_a2,
    const float* __restrict__ p_s6, const float* __restrict__ p_s8,
    float* __restrict__ partial, int* __restrict__ cnt,
    float* __restrict__ out)
{
    const int tid  = threadIdx.x;
    const int lane = tid & 63;
    const int w = __builtin_amdgcn_readfirstlane(blockIdx.x * WPB + (tid >> 6));

    // ---- decode w -> (I, J) with J in [2I, 128)
    int I = (int)((129.0f - sqrtf(16641.0f - 4.0f * (float)w)) * 0.5f);
    if (I < 0) I = 0;
    if (I > NI - 1) I = NI - 1;
    while (S_OF(I + 1) <= w) ++I;
    while (S_OF(I) > w) --I;
    const int J = 2 * I + (w - S_OF(I));
    const bool edge = (w - S_OF(I)) < 2;   // J in {2I, 2I+1}: contains j<=i cells

    // ---- positions pre-scaled by 2^-6 (exact): d2' = 2^-12 d2, d6' = 2^-36 d6, d8' = 2^-48 d8
    const float PS = 0.015625f;            // 2^-6
    const int j = J * JT + lane;
    const float vxj = pos[3 * j + 0] * PS; // broadcast source, held in VGPRs
    const float vyj = pos[3 * j + 1] * PS;
    const float vzj = pos[3 * j + 2] * PS;

    const int i0 = I * IT + 2 * lane;      // lane owns atoms i0, i0+1
    const v2f xi = { pos[3 * i0 + 0] * PS, pos[3 * i0 + 3] * PS };
    const v2f yi = { pos[3 * i0 + 1] * PS, pos[3 * i0 + 4] * PS };
    const v2f zi = { pos[3 * i0 + 2] * PS, pos[3 * i0 + 5] * PS };

    const float a1 = p_a1[0], a2 = p_a2[0];
    const float s6 = p_s6[0], s8 = p_s8[0];
    const float tmp  = a1 + a2;
    const float tmp2 = tmp * tmp;
    const float tmp6 = tmp2 * tmp2 * tmp2;
    const float tmp8 = tmp6 * tmp2;
    // scaled constants: A' = 2^-36 (d6+T6), B' = 2^-48 (d8+T8)
    const float T6s = (tmp6 + 1e-12f) * 1.4551915e-11f;   // * 2^-36
    const float T8s = (tmp8 + 1e-12f) * 3.5527137e-15f;   // * 2^-48
    // term = -(s6*2^-36 * B' + s8*2^-48 * A') / (A'B');  fold the (i,j)+(j,i) doubling (x2)
    const float c6 = -2.0f * s6 * 1.4551915e-11f;
    const float c8 = -2.0f * s8 * 3.5527137e-15f;

    float accx = 0.0f, accy = 0.0f;

    auto body = [&](int k, bool masked) {
        float sx = bcast(vxj, k);          // j-atom k broadcast (SGPR splat operand)
        float sy = bcast(vyj, k);
        float sz = bcast(vzj, k);
        v2f dx = xi - sx;
        v2f dy = yi - sy;
        v2f dz = zi - sz;
        v2f d2 = __builtin_elementwise_fma(dx, dx,
                 __builtin_elementwise_fma(dy, dy, dz * dz));
        v2f d4 = d2 * d2;
        v2f A  = __builtin_elementwise_fma(d4, d2, (v2f)T6s);  // 2^-36 (d6+T6)
        v2f B  = __builtin_elementwise_fma(d4, d4, (v2f)T8s);  // 2^-48 (d8+T8)
        v2f num = __builtin_elementwise_fma((v2f)c6, B, (v2f)c8 * A);
        v2f den = A * B;                   // in [2e-16, 8.8e2]: safe
        float t = den.x * den.y;           // in [4e-32, 7.7e5]: safe
        float r = __builtin_amdgcn_rcpf(t);    // ONE rcp for both pairs
        float numx = num.x, numy = num.y;
        if (masked) {                      // edge jobs: count only j>i (excludes self)
            const int jk = J * JT + k;
            numx = (jk > i0)     ? numx : 0.0f;
            numy = (jk > i0 + 1) ? numy : 0.0f;
        }
        accx = fmaf(numx, den.y * r, accx);    // num/den.x
        accy = fmaf(numy, den.x * r, accy);    // num/den.y
    };

    if (edge) {
        #pragma unroll 8
        for (int k = 0; k < JT; ++k) body(k, true);
    } else {
        #pragma unroll 8
        for (int k = 0; k < JT; ++k) body(k, false);
    }

    float acc = accx + accy;               // doubling already folded into c6/c8

    // ---- wave butterfly, block partial, counter-gated final reduce
    #pragma unroll
    for (int off = 32; off > 0; off >>= 1)
        acc += __shfl_xor(acc, off, 64);

    __shared__ float wsum[WPB];
    __shared__ int lastflag;
    if (lane == 0) wsum[tid >> 6] = acc;
    __syncthreads();
    if (tid == 0) {
        float s = 0.0f;
        #pragma unroll
        for (int q = 0; q < WPB; ++q) s += wsum[q];
        atomicExch(&partial[blockIdx.x], s);   // device-coherent block sum
        __threadfence();                       // release: partial before counter
        int old = atomicAdd(cnt, 1);
        lastflag = (old == NBLK - 1);
    }
    __syncthreads();
    if (lastflag) {
        __threadfence();                       // acquire
        float s = 0.0f;
        for (int t = tid; t < NBLK; t += BLOCK)
            s += atomicAdd(&partial[t], 0.0f); // coherent read
        #pragma unroll
        for (int off = 32; off > 0; off >>= 1)
            s += __shfl_xor(s, off, 64);
        if (lane == 0) wsum[tid >> 6] = s;
        __syncthreads();
        if (tid == 0) {
            float tot = 0.0f;
            #pragma unroll
            for (int q = 0; q < WPB; ++q) tot += wsum[q];
            out[0] = tot;
        }
    }
}

extern "C" void kernel_launch(void* const* d_in, const int* in_sizes, int n_in,
                              void* d_out, int out_size, void* d_ws, size_t ws_size,
                              hipStream_t stream) {
    // setup_inputs order: atomic_numbers(0), positions(1), r2r4(2), a1(3), a2(4), s6(5), s8(6)
    const float* pos = (const float*)d_in[1];
    const float* a1  = (const float*)d_in[3];
    const float* a2  = (const float*)d_in[4];
    const float* s6  = (const float*)d_in[5];
    const float* s8  = (const float*)d_in[6];
    float* partial = (float*)d_ws;                    // NBLK block sums
    int*   cnt     = (int*)((char*)d_ws + 65536);     // arrival counter
    float* out     = (float*)d_out;

    hipMemsetAsync(cnt, 0, sizeof(int), stream);      // 4 bytes only

    dftd3_pair_energy<<<dim3(NBLK), BLOCK, 0, stream>>>(pos, a1, a2, s6, s8,
                                                        partial, cnt, out);
}